// Round 7
// baseline (222.018 us; speedup 1.0000x reference)
//
#include <hip/hip_runtime.h>

#define EPS 1e-5f

typedef __bf16 bf16x8 __attribute__((ext_vector_type(8)));
typedef float  f32x4  __attribute__((ext_vector_type(4)));

__device__ __forceinline__ unsigned short f2bf(float f) {
  unsigned int u = __float_as_uint(f);
  unsigned int r = (u + 0x7fffu + ((u >> 16) & 1u)) >> 16;
  return (unsigned short)r;
}
// silu via v_rcp_f32 (avoids the precise-div sequence; ~2^-22 rel err, fine at bf16 tol)
__device__ __forceinline__ float silu(float y) {
  return y * __builtin_amdgcn_rcpf(1.f + __expf(-y));
}

// ---------------- prep:
// blk 0..399   : feat = SiLU(BN(conv1x1(x,w1))) for 2 px; zero att rows q>=200; zero flags
// blk 400..471 : pack wr2 -> MFMA A-frag bf16 (frag f = tap*32+ks*8+m8)
// blk 472..503 : wave-parallel prefix sums of wr1 rows -> Pfx[o][0..256]
// blk 504..647 : transpose wr2 -> Wt[tap][i][o] fp32
// blk 648..711 : transpose w2 -> W2t[i][o] fp32
__global__ void prep_kernel(const float* __restrict__ x, const float* __restrict__ w1,
                            const float* __restrict__ g1, const float* __restrict__ b1,
                            const float* __restrict__ m1, const float* __restrict__ v1,
                            const float* __restrict__ wr2, const float* __restrict__ wr1,
                            const float* __restrict__ w2,
                            float* __restrict__ feat, float* __restrict__ attz,
                            unsigned short* __restrict__ Apack, float* __restrict__ Pfx,
                            float* __restrict__ Wt, float* __restrict__ W2t,
                            int* __restrict__ flags) {
  int blk = blockIdx.x;
  int tid = threadIdx.x;
  if (blk < 400) {
    if (tid < 2) flags[blk * 2 + tid] = 0;
    int hp = tid >> 7, c = tid & 127;
    int pp = blk * 2 + hp;
    int b = pp / 400, p = pp % 400;
    __shared__ float xv[2][128];
    xv[hp][c] = x[(b * 128 + c) * 400 + p];
    __syncthreads();
    const float4* w4 = (const float4*)(w1 + c * 128);
    const float4* v4 = (const float4*)xv[hp];
    float s0 = 0.f, s1 = 0.f, s2 = 0.f, s3 = 0.f;
#pragma unroll
    for (int i = 0; i < 32; ++i) {
      float4 wv = w4[i], xx = v4[i];
      s0 += wv.x * xx.x; s1 += wv.y * xx.y; s2 += wv.z * xx.z; s3 += wv.w * xx.w;
    }
    float s = (s0 + s1) + (s2 + s3);
    float sc = g1[c] * rsqrtf(v1[c] + EPS);
    float y = s * sc + (b1[c] - m1[c] * sc);
    int o = (b * 400 + p) * 128 + c;
    feat[o] = silu(y);
    if (p >= 200) attz[o] = 0.f;
  } else if (blk < 472) {
    int f = (blk - 400) * 4 + (tid >> 6);
    int lane = tid & 63;
    int tap = f >> 5, ks = (f >> 3) & 3, m8 = f & 7;
    int o  = m8 * 16 + (lane & 15);
    int cb = ks * 32 + (lane >> 4) * 8;
    unsigned short* dst = Apack + ((size_t)f * 64 + lane) * 8;
#pragma unroll
    for (int j = 0; j < 8; ++j)
      dst[j] = f2bf(wr2[(o * 128 + (cb + j)) * 9 + tap]);
  } else if (blk < 504) {
    int o = (blk - 472) * 4 + (tid >> 6);
    int lane = tid & 63;
    float4 wv = ((const float4*)(wr1 + o * 256))[lane];
    float p0 = wv.x, p1 = p0 + wv.y, p2 = p1 + wv.z, p3 = p2 + wv.w;
    float v = p3;
#pragma unroll
    for (int d = 1; d < 64; d <<= 1) {
      float t = __shfl_up(v, d);
      if (lane >= d) v += t;
    }
    float off = v - p3;
    float* Po = Pfx + o * 257;
    if (lane == 0) Po[0] = 0.f;
    Po[lane * 4 + 1] = off + p0;
    Po[lane * 4 + 2] = off + p1;
    Po[lane * 4 + 3] = off + p2;
    Po[lane * 4 + 4] = off + p3;
  } else if (blk < 648) {
    int base = (blk - 504) * 1024;
#pragma unroll
    for (int k = 0; k < 4; ++k) {
      int idx = base + k * 256 + tid;            // < 147456
      int tap = idx >> 14;
      int r = idx & 16383;
      int i = r >> 7, o = r & 127;
      Wt[idx] = wr2[(o * 128 + i) * 9 + tap];
    }
  } else {
    int idx = (blk - 648) * 256 + tid;           // < 16384
    int i = idx >> 7, o = idx & 127;
    W2t[idx] = w2[o * 128 + i];
  }
}

// ---------------- merged relational + output kernel
// blk 0..799   : main path, q in [200,400), half-image; second-finishing half fuses out-conv
// blk 800..1199: const path, q in [0,200); computes out row inline (no global att round-trip)
__global__ __launch_bounds__(512, 4) void rel_kernel(
    const float* __restrict__ feat, const float* __restrict__ wr1, const float* __restrict__ Pfx,
    const float* __restrict__ gr1, const float* __restrict__ br1,
    const float* __restrict__ mr1, const float* __restrict__ vr1,
    const unsigned short* __restrict__ Apack, const float* __restrict__ Wt,
    const float* __restrict__ gr2, const float* __restrict__ br2,
    const float* __restrict__ mr2, const float* __restrict__ vr2,
    const float* __restrict__ wr3,
    const float* __restrict__ gr3, const float* __restrict__ br3,
    const float* __restrict__ mr3, const float* __restrict__ vr3,
    const float* __restrict__ W2t, const float* __restrict__ g2,
    const float* __restrict__ b2, const float* __restrict__ m2,
    const float* __restrict__ v2, const float* __restrict__ x,
    float* __restrict__ att, float* __restrict__ out, int* __restrict__ flags) {

  __shared__ __align__(16) unsigned short r1f[16 * 221 * 8];   // 56576 B
  __shared__ float f0s[220], f1s[220], scoreS[208];
  __shared__ float wB0s[128], wB1s[128];
  __shared__ float sc1[128], sh1[128], sc2[128], sh2[128], w3c[128];
  __shared__ float attT[128], outT[128];
  __shared__ float fA[256], r1c[128], AvS[128];
  __shared__ float vS[9 * 128];
  __shared__ float spS[9];
  __shared__ float spP[400];
  __shared__ int   secondFlag;

  int tid = threadIdx.x, lane = tid & 63, wid = tid >> 6;
  int blk = blockIdx.x;

  if (tid < 128) {
    float s1 = gr1[tid] * rsqrtf(vr1[tid] + EPS); sc1[tid] = s1; sh1[tid] = br1[tid] - mr1[tid] * s1;
    float s2 = gr2[tid] * rsqrtf(vr2[tid] + EPS); sc2[tid] = s2; sh2[tid] = br2[tid] - mr2[tid] * s2;
    w3c[tid] = wr3[tid];
    attT[tid] = 0.f; outT[tid] = 0.f; AvS[tid] = 0.f;
  }
  float s3 = gr3[0] * rsqrtf(vr3[0] + EPS);
  float sh3 = br3[0] - mr3[0] * s3;

  if (blk < 800) {
    // ================= main path =================
    int idx = blk >> 1, half = blk & 1;
    int b = idx / 200, q = 200 + idx % 200;
    int row = b * 400 + q;
    int c0 = (q * 256) / 400, c1 = c0 + 1;
    if (tid < 128) {
      const float* Po = Pfx + tid * 257;
      int e0 = min(256, 400 * c0 + 400 - 256 * q);   // s0 is always 0
      wB0s[tid] = Po[e0];
      float wv = 0.f;
      if (c1 < 256) {
        int s1i = min(256, max(0, 400 * c1 - 256 * q));
        wv = Po[256] - Po[s1i];
      }
      wB1s[tid] = wv;
    }
    if (tid < 220) {
      int p = tid + 180 * half;
      f0s[tid] = feat[(b * 400 + p) * 128 + (c0 - 128)];
      f1s[tid] = (c1 < 256) ? feat[(b * 400 + p) * 128 + (c1 - 128)] : 0.f;
    }
    if (tid < 208) scoreS[tid] = 0.f;
    __syncthreads();

    // phase1: r1 = SiLU(BN(wB0*f0 + wB1*f1)) -> LDS bf16 fragment-major
    for (int i = tid; i < 3520; i += 512) {
      int plane = i / 220, p = i - plane * 220;
      int cb = (plane >> 2) * 32 + (plane & 3) * 8;
      float fa0 = f0s[p], fa1 = f1s[p];
      unsigned int pk[4];
#pragma unroll
      for (int jp = 0; jp < 4; ++jp) {
        int c = cb + jp * 2;
        float y0 = wB0s[c] * fa0 + wB1s[c] * fa1;     y0 = y0 * sc1[c] + sh1[c];
        float y1 = wB0s[c + 1] * fa0 + wB1s[c + 1] * fa1; y1 = y1 * sc1[c + 1] + sh1[c + 1];
        pk[jp] = (unsigned int)f2bf(silu(y0)) | ((unsigned int)f2bf(silu(y1)) << 16);
      }
      *(uint4*)&r1f[(plane * 221 + p) * 8] = make_uint4(pk[0], pk[1], pk[2], pk[3]);
    }
    if (tid < 16) *(uint4*)&r1f[(tid * 221 + 220) * 8] = make_uint4(0, 0, 0, 0);

    int wm = wid & 1, wn = wid >> 1;
    int ntcnt = (wn == 0) ? 4 : 3;
    int n16 = lane & 15, quad = lane >> 4;
    int hA[4], wA[4], poA[4]; bool pov[4];
#pragma unroll
    for (int t = 0; t < 4; ++t) {
      int po = (wn + 4 * t) * 16 + n16;
      poA[t] = po; pov[t] = po < 200;
      int pg = half * 200 + po;
      hA[t] = pg / 20; wA[t] = pg - 20 * hA[t];
    }
    f32x4 acc[4][4];
#pragma unroll
    for (int mt = 0; mt < 4; ++mt)
#pragma unroll
      for (int t = 0; t < 4; ++t) acc[mt][t] = f32x4{0.f, 0.f, 0.f, 0.f};

    __syncthreads();   // r1f visible — NO barriers through the K-loop

    const char* wbase = (const char*)Apack + (size_t)((wm * 4) * 64 + lane) * 16;
    for (int tap = 0; tap < 9; ++tap) {
      int dy = tap / 3 - 1, dx = tap % 3 - 1;
      int pp[4];
#pragma unroll
      for (int t = 0; t < 4; ++t) {
        int hh = hA[t] + dy, ww = wA[t] + dx;
        bool valid = pov[t] & (hh >= 0) & (hh < 20) & (ww >= 0) & (ww < 20);
        pp[t] = valid ? (hh - 9 * half) * 20 + ww : 220;
      }
#pragma unroll
      for (int ks = 0; ks < 4; ++ks) {
        const char* wp = wbase + (size_t)(tap * 4 + ks) * 8192;
        bf16x8 af0 = *(const bf16x8*)(wp);
        bf16x8 af1 = *(const bf16x8*)(wp + 1024);
        bf16x8 af2 = *(const bf16x8*)(wp + 2048);
        bf16x8 af3 = *(const bf16x8*)(wp + 3072);
        int pbase = (ks * 4 + quad) * 221;
#pragma unroll
        for (int t = 0; t < 4; ++t) {
          if (t < ntcnt) {                 // wave-uniform
            bf16x8 bfr = *(const bf16x8*)&r1f[(pbase + pp[t]) * 8];
            acc[0][t] = __builtin_amdgcn_mfma_f32_16x16x32_bf16(af0, bfr, acc[0][t], 0, 0, 0);
            acc[1][t] = __builtin_amdgcn_mfma_f32_16x16x32_bf16(af1, bfr, acc[1][t], 0, 0, 0);
            acc[2][t] = __builtin_amdgcn_mfma_f32_16x16x32_bf16(af2, bfr, acc[2][t], 0, 0, 0);
            acc[3][t] = __builtin_amdgcn_mfma_f32_16x16x32_bf16(af3, bfr, acc[3][t], 0, 0, 0);
          }
        }
      }
    }

    // epilogue: BN2+SiLU, conv3 dot, reduce to scoreS
#pragma unroll
    for (int t = 0; t < 4; ++t) {
      if (t < ntcnt) {
        float ps = 0.f;
#pragma unroll
        for (int mt = 0; mt < 4; ++mt) {
#pragma unroll
          for (int r = 0; r < 4; ++r) {
            int o = wm * 64 + mt * 16 + quad * 4 + r;
            float y = acc[mt][t][r] * sc2[o] + sh2[o];
            ps += silu(y) * w3c[o];
          }
        }
        ps += __shfl_xor(ps, 16);
        ps += __shfl_xor(ps, 32);
        if (quad == 0 && pov[t]) atomicAdd(&scoreS[poA[t]], ps);
      }
    }
    __syncthreads();

    if (tid < 200) scoreS[tid] = silu(scoreS[tid] * s3 + sh3);
    __syncthreads();

    {
      int c = tid & 127, part = tid >> 7;
      float s = 0.f;
      int j0 = part * 50;
      for (int j = j0; j < j0 + 50; ++j)
        s += scoreS[j] * feat[(b * 400 + half * 200 + j) * 128 + c];
      atomicAdd(&attT[c], s);
    }
    __syncthreads();
    if (tid < 128)
      atomicAdd(&att[(size_t)row * 128 + tid], attT[tid]);  // 2 addends: exact
    __syncthreads();   // drains the atomic stores (vmcnt) for all threads
    if (tid == 0) {
      __threadfence();
      secondFlag = (atomicAdd(&flags[row], 1) == 1);
    }
    __syncthreads();

    if (secondFlag) {
      // fused out-conv for this row: att row is complete at device scope
      if (tid < 128)
        attT[tid] = __hip_atomic_load(&att[(size_t)row * 128 + tid],
                                      __ATOMIC_RELAXED, __HIP_MEMORY_SCOPE_AGENT);
      __syncthreads();
      int c = tid & 127, part = tid >> 7;
      const float* wt = W2t + part * 32 * 128 + c;
      const float* af = attT + part * 32;
      float s = 0.f;
#pragma unroll 8
      for (int k = 0; k < 32; ++k) s += wt[k * 128] * af[k];
      atomicAdd(&outT[c], s);
      __syncthreads();
      if (tid < 128) {
        float sc = g2[tid] * rsqrtf(v2[tid] + EPS);
        float y = outT[tid] * sc + (b2[tid] - m2[tid] * sc);
        int xi = (b * 128 + tid) * 400 + q;
        out[xi] = silu(y) + x[xi];
      }
    }
  } else {
    // ================= const path (q < 200): r1 constant over pixels =================
    int cidx = blk - 800;
    int b = cidx / 200, q = cidx % 200;
    if (tid < 256) {
      int u = q * 256 + tid; int c = u / 400, i2 = u - c * 400;
      fA[tid] = feat[(b * 400 + i2) * 128 + c];            // all c < 128 here
    }
    for (int k = tid; k < 1152; k += 512) vS[k] = 0.f;
    __syncthreads();
    {
      int o = tid & 127, part = tid >> 7;
      const float* wr = wr1 + o * 256 + part * 64;
      const float* fv = fA + part * 64;
      float a = 0.f;
#pragma unroll 8
      for (int k = 0; k < 64; ++k) a += wr[k] * fv[k];
      atomicAdd(&AvS[o], a);
    }
    __syncthreads();
    if (tid < 128) r1c[tid] = silu(AvS[tid] * sc1[tid] + sh1[tid]);
    __syncthreads();
    {
      int o = tid & 127, part = tid >> 7;
      const float* rc = r1c + part * 32;
      for (int tap = 0; tap < 9; ++tap) {
        const float* wt = Wt + tap * 16384 + part * 32 * 128 + o;
        float s = 0.f;
#pragma unroll 8
        for (int i2 = 0; i2 < 32; ++i2) s += wt[i2 * 128] * rc[i2];
        atomicAdd(&vS[tap * 128 + o], s);
      }
    }
    __syncthreads();
    for (int pat = wid; pat < 9; pat += 8) {
      int ry = pat / 3, rx = pat % 3;
      float ps = 0.f;
      for (int oo = lane; oo < 128; oo += 64) {
        float y = 0.f;
#pragma unroll
        for (int dy = -1; dy <= 1; ++dy) {
          if ((ry == 0 && dy < 0) || (ry == 2 && dy > 0)) continue;
#pragma unroll
          for (int dx = -1; dx <= 1; ++dx) {
            if ((rx == 0 && dx < 0) || (rx == 2 && dx > 0)) continue;
            y += vS[((dy + 1) * 3 + (dx + 1)) * 128 + oo];
          }
        }
        y = y * sc2[oo] + sh2[oo];
        ps += silu(y) * w3c[oo];
      }
#pragma unroll
      for (int sft = 32; sft >= 1; sft >>= 1) ps += __shfl_xor(ps, sft);
      if (lane == 0) spS[pat] = silu(ps * s3 + sh3);
    }
    __syncthreads();

    for (int p = tid; p < 400; p += 512) {
      int r = p / 20, cm = p - 20 * r;
      int ry = (r == 0) ? 0 : (r == 19) ? 2 : 1;
      int rx = (cm == 0) ? 0 : (cm == 19) ? 2 : 1;
      spP[p] = spS[ry * 3 + rx];
    }
    __syncthreads();
    {
      int c = tid & 127, part = tid >> 7;
      const float* fb = feat + ((size_t)(b * 400) + part * 100) * 128 + c;
      const float* sp = spP + part * 100;
      float s = 0.f;
      for (int j = 0; j < 100; ++j) s += sp[j] * fb[(size_t)j * 128];
      atomicAdd(&attT[c], s);
    }
    __syncthreads();

    // fused out-conv directly from LDS attT (no global att round-trip)
    {
      int c = tid & 127, part = tid >> 7;
      const float* wt = W2t + part * 32 * 128 + c;
      const float* af = attT + part * 32;
      float s = 0.f;
#pragma unroll 8
      for (int k = 0; k < 32; ++k) s += wt[k * 128] * af[k];
      atomicAdd(&outT[c], s);
    }
    __syncthreads();
    if (tid < 128) {
      float sc = g2[tid] * rsqrtf(v2[tid] + EPS);
      float y = outT[tid] * sc + (b2[tid] - m2[tid] * sc);
      int xi = (b * 128 + tid) * 400 + q;
      out[xi] = silu(y) + x[xi];
    }
  }
}

extern "C" void kernel_launch(void* const* d_in, const int* in_sizes, int n_in,
                              void* d_out, int out_size, void* d_ws, size_t ws_size,
                              hipStream_t stream) {
  const float* x   = (const float*)d_in[0];
  const float* w1  = (const float*)d_in[1];
  const float* g1  = (const float*)d_in[2];
  const float* b1  = (const float*)d_in[3];
  const float* m1  = (const float*)d_in[4];
  const float* v1  = (const float*)d_in[5];
  const float* w2  = (const float*)d_in[6];
  const float* g2  = (const float*)d_in[7];
  const float* b2  = (const float*)d_in[8];
  const float* m2  = (const float*)d_in[9];
  const float* v2  = (const float*)d_in[10];
  const float* wr1 = (const float*)d_in[11];
  const float* gr1 = (const float*)d_in[12];
  const float* br1 = (const float*)d_in[13];
  const float* mr1 = (const float*)d_in[14];
  const float* vr1 = (const float*)d_in[15];
  const float* wr2 = (const float*)d_in[16];
  const float* gr2 = (const float*)d_in[17];
  const float* br2 = (const float*)d_in[18];
  const float* mr2 = (const float*)d_in[19];
  const float* vr2 = (const float*)d_in[20];
  const float* wr3 = (const float*)d_in[21];
  const float* gr3 = (const float*)d_in[22];
  const float* br3 = (const float*)d_in[23];
  const float* mr3 = (const float*)d_in[24];
  const float* vr3 = (const float*)d_in[25];
  float* out = (float*)d_out;

  char* ws = (char*)d_ws;
  float*          feat  = (float*)ws;                        // 409600 B
  float*          attb  = (float*)(ws + 409600);             // 409600 B
  unsigned short* Apack = (unsigned short*)(ws + 819200);    // 294912 B
  float*          Pfx   = (float*)(ws + 1114112);            // 131584 B
  float*          Wt    = (float*)(ws + 1245696);            // 589824 B
  float*          W2t   = (float*)(ws + 1835520);            //  65536 B
  int*            flags = (int*)(ws + 1901056);              //   3200 B

  prep_kernel<<<712, 256, 0, stream>>>(x, w1, g1, b1, m1, v1, wr2, wr1, w2,
                                       feat, attb, Apack, Pfx, Wt, W2t, flags);
  rel_kernel<<<1200, 512, 0, stream>>>(feat, wr1, Pfx, gr1, br1, mr1, vr1,
                                       Apack, Wt,
                                       gr2, br2, mr2, vr2, wr3, gr3, br3, mr3, vr3,
                                       W2t, g2, b2, m2, v2, x, attb, out, flags);
}

// Round 8
// 201.452 us; speedup vs baseline: 1.1021x; 1.1021x over previous
//
#include <hip/hip_runtime.h>

#define EPS 1e-5f

typedef __bf16 bf16x8 __attribute__((ext_vector_type(8)));
typedef float  f32x4  __attribute__((ext_vector_type(4)));

__device__ __forceinline__ unsigned short f2bf(float f) {
  unsigned int u = __float_as_uint(f);
  unsigned int r = (u + 0x7fffu + ((u >> 16) & 1u)) >> 16;
  return (unsigned short)r;
}
// silu via v_rcp_f32 (avoids precise-div sequence; ~2^-22 rel err, fine at bf16 tol)
__device__ __forceinline__ float silu(float y) {
  return y * __builtin_amdgcn_rcpf(1.f + __expf(-y));
}

// ---------------- prep:
// blk 0..399   : feat + featT = SiLU(BN(conv1x1(x,w1))) for 2 px; zero att rows q>=200
// blk 400..471 : pack wr2 -> MFMA A-frag bf16 (frag f = tap*32+ks*8+m8)
// blk 472..503 : wave-parallel prefix sums of wr1 rows -> Pfx[o][0..256]
// blk 504..647 : transpose wr2 -> Wt[tap][i][o] fp32
// blk 648..711 : transpose w2 -> W2t[i][o] fp32
// blk 712..743 : transpose wr1 -> wr1T[i][o] fp32
__global__ void prep_kernel(const float* __restrict__ x, const float* __restrict__ w1,
                            const float* __restrict__ g1, const float* __restrict__ b1,
                            const float* __restrict__ m1, const float* __restrict__ v1,
                            const float* __restrict__ wr2, const float* __restrict__ wr1,
                            const float* __restrict__ w2,
                            float* __restrict__ feat, float* __restrict__ featT,
                            float* __restrict__ attz,
                            unsigned short* __restrict__ Apack, float* __restrict__ Pfx,
                            float* __restrict__ Wt, float* __restrict__ W2t,
                            float* __restrict__ wr1T) {
  int blk = blockIdx.x;
  int tid = threadIdx.x;
  if (blk < 400) {
    int hp = tid >> 7, c = tid & 127;
    int pp = blk * 2 + hp;
    int b = pp / 400, p = pp % 400;
    __shared__ float xv[2][128];
    xv[hp][c] = x[(b * 128 + c) * 400 + p];
    __syncthreads();
    const float4* w4 = (const float4*)(w1 + c * 128);
    const float4* v4 = (const float4*)xv[hp];
    float s0 = 0.f, s1 = 0.f, s2 = 0.f, s3 = 0.f;
#pragma unroll
    for (int i = 0; i < 32; ++i) {
      float4 wv = w4[i], xx = v4[i];
      s0 += wv.x * xx.x; s1 += wv.y * xx.y; s2 += wv.z * xx.z; s3 += wv.w * xx.w;
    }
    float s = (s0 + s1) + (s2 + s3);
    float sc = g1[c] * rsqrtf(v1[c] + EPS);
    float y = s * sc + (b1[c] - m1[c] * sc);
    float f = silu(y);
    feat[(b * 400 + p) * 128 + c] = f;
    featT[(b * 128 + c) * 400 + p] = f;
    if (p >= 200) attz[(b * 400 + p) * 128 + c] = 0.f;
  } else if (blk < 472) {
    int f = (blk - 400) * 4 + (tid >> 6);
    int lane = tid & 63;
    int tap = f >> 5, ks = (f >> 3) & 3, m8 = f & 7;
    int o  = m8 * 16 + (lane & 15);
    int cb = ks * 32 + (lane >> 4) * 8;
    unsigned short* dst = Apack + ((size_t)f * 64 + lane) * 8;
#pragma unroll
    for (int j = 0; j < 8; ++j)
      dst[j] = f2bf(wr2[(o * 128 + (cb + j)) * 9 + tap]);
  } else if (blk < 504) {
    int o = (blk - 472) * 4 + (tid >> 6);
    int lane = tid & 63;
    float4 wv = ((const float4*)(wr1 + o * 256))[lane];
    float p0 = wv.x, p1 = p0 + wv.y, p2 = p1 + wv.z, p3 = p2 + wv.w;
    float v = p3;
#pragma unroll
    for (int d = 1; d < 64; d <<= 1) {
      float t = __shfl_up(v, d);
      if (lane >= d) v += t;
    }
    float off = v - p3;
    float* Po = Pfx + o * 257;
    if (lane == 0) Po[0] = 0.f;
    Po[lane * 4 + 1] = off + p0;
    Po[lane * 4 + 2] = off + p1;
    Po[lane * 4 + 3] = off + p2;
    Po[lane * 4 + 4] = off + p3;
  } else if (blk < 648) {
    int base = (blk - 504) * 1024;
#pragma unroll
    for (int k = 0; k < 4; ++k) {
      int idx = base + k * 256 + tid;            // < 147456
      int tap = idx >> 14;
      int r = idx & 16383;
      int i = r >> 7, o = r & 127;
      Wt[idx] = wr2[(o * 128 + i) * 9 + tap];
    }
  } else if (blk < 712) {
    int idx = (blk - 648) * 256 + tid;           // < 16384
    int i = idx >> 7, o = idx & 127;
    W2t[idx] = w2[o * 128 + i];
  } else {
    int base = (blk - 712) * 1024;
#pragma unroll
    for (int k = 0; k < 4; ++k) {
      int idx = base + k * 256 + tid;            // < 32768
      int i = idx >> 7, o = idx & 127;
      wr1T[idx] = wr1[o * 256 + i];
    }
  }
}

// ---------------- merged relational kernel
// blk 0..799   : main path, q in [200,400), half-image (barrier-free MFMA K-loop)
// blk 800..1199: const path, q in [0,200) (r1 spatially constant -> 9-pattern shortcut)
__global__ __launch_bounds__(512, 4) void rel_kernel(
    const float* __restrict__ feat, const float* __restrict__ featT,
    const float* __restrict__ wr1T, const float* __restrict__ Pfx,
    const float* __restrict__ gr1, const float* __restrict__ br1,
    const float* __restrict__ mr1, const float* __restrict__ vr1,
    const unsigned short* __restrict__ Apack, const float* __restrict__ Wt,
    const float* __restrict__ gr2, const float* __restrict__ br2,
    const float* __restrict__ mr2, const float* __restrict__ vr2,
    const float* __restrict__ wr3,
    const float* __restrict__ gr3, const float* __restrict__ br3,
    const float* __restrict__ mr3, const float* __restrict__ vr3,
    float* __restrict__ att) {

  __shared__ __align__(16) unsigned short r1f[16 * 221 * 8];   // 56576 B
  __shared__ float f0s[220], f1s[220], scoreS[208];
  __shared__ float wB0s[128], wB1s[128];
  __shared__ float sc1[128], sh1[128], sc2[128], sh2[128], w3c[128];
  __shared__ float attT[128];
  __shared__ float fA[256], r1c[128], AvS[128];
  __shared__ float vS[9 * 128];
  __shared__ float spS[9];
  __shared__ float spP[400];

  int tid = threadIdx.x, lane = tid & 63, wid = tid >> 6;
  int blk = blockIdx.x;

  if (tid < 128) {
    float s1 = gr1[tid] * rsqrtf(vr1[tid] + EPS); sc1[tid] = s1; sh1[tid] = br1[tid] - mr1[tid] * s1;
    float s2 = gr2[tid] * rsqrtf(vr2[tid] + EPS); sc2[tid] = s2; sh2[tid] = br2[tid] - mr2[tid] * s2;
    w3c[tid] = wr3[tid];
    attT[tid] = 0.f; AvS[tid] = 0.f;
  }
  float s3 = gr3[0] * rsqrtf(vr3[0] + EPS);
  float sh3 = br3[0] - mr3[0] * s3;

  if (blk < 800) {
    // ================= main path =================
    int idx = blk >> 1, half = blk & 1;
    int b = idx / 200, q = 200 + idx % 200;
    int c0 = (q * 256) / 400, c1 = c0 + 1;
    if (tid < 128) {
      const float* Po = Pfx + tid * 257;
      int e0 = min(256, 400 * c0 + 400 - 256 * q);   // s0 is always 0
      wB0s[tid] = Po[e0];
      float wv = 0.f;
      if (c1 < 256) {
        int s1i = min(256, max(0, 400 * c1 - 256 * q));
        wv = Po[256] - Po[s1i];
      }
      wB1s[tid] = wv;
    }
    if (tid < 220) {
      int p = tid + 180 * half;
      f0s[tid] = featT[(b * 128 + (c0 - 128)) * 400 + p];                  // coalesced
      f1s[tid] = (c1 < 256) ? featT[(b * 128 + (c1 - 128)) * 400 + p] : 0.f;
    }
    if (tid < 208) scoreS[tid] = 0.f;
    __syncthreads();

    // phase1: r1 = SiLU(BN(wB0*f0 + wB1*f1)) -> LDS bf16 fragment-major
    for (int i = tid; i < 3520; i += 512) {
      int plane = i / 220, p = i - plane * 220;
      int cb = (plane >> 2) * 32 + (plane & 3) * 8;
      float fa0 = f0s[p], fa1 = f1s[p];
      unsigned int pk[4];
#pragma unroll
      for (int jp = 0; jp < 4; ++jp) {
        int c = cb + jp * 2;
        float y0 = wB0s[c] * fa0 + wB1s[c] * fa1;     y0 = y0 * sc1[c] + sh1[c];
        float y1 = wB0s[c + 1] * fa0 + wB1s[c + 1] * fa1; y1 = y1 * sc1[c + 1] + sh1[c + 1];
        pk[jp] = (unsigned int)f2bf(silu(y0)) | ((unsigned int)f2bf(silu(y1)) << 16);
      }
      *(uint4*)&r1f[(plane * 221 + p) * 8] = make_uint4(pk[0], pk[1], pk[2], pk[3]);
    }
    if (tid < 16) *(uint4*)&r1f[(tid * 221 + 220) * 8] = make_uint4(0, 0, 0, 0);

    int wm = wid & 1, wn = wid >> 1;
    int ntcnt = (wn == 0) ? 4 : 3;
    int n16 = lane & 15, quad = lane >> 4;
    int hA[4], wA[4], poA[4]; bool pov[4];
#pragma unroll
    for (int t = 0; t < 4; ++t) {
      int po = (wn + 4 * t) * 16 + n16;
      poA[t] = po; pov[t] = po < 200;
      int pg = half * 200 + po;
      hA[t] = pg / 20; wA[t] = pg - 20 * hA[t];
    }
    f32x4 acc[4][4];
#pragma unroll
    for (int mt = 0; mt < 4; ++mt)
#pragma unroll
      for (int t = 0; t < 4; ++t) acc[mt][t] = f32x4{0.f, 0.f, 0.f, 0.f};

    __syncthreads();   // r1f visible — NO barriers through the K-loop

    const char* wbase = (const char*)Apack + (size_t)((wm * 4) * 64 + lane) * 16;
    for (int tap = 0; tap < 9; ++tap) {
      int dy = tap / 3 - 1, dx = tap % 3 - 1;
      int pp[4];
#pragma unroll
      for (int t = 0; t < 4; ++t) {
        int hh = hA[t] + dy, ww = wA[t] + dx;
        bool valid = pov[t] & (hh >= 0) & (hh < 20) & (ww >= 0) & (ww < 20);
        pp[t] = valid ? (hh - 9 * half) * 20 + ww : 220;
      }
#pragma unroll
      for (int ks = 0; ks < 4; ++ks) {
        const char* wp = wbase + (size_t)(tap * 4 + ks) * 8192;
        bf16x8 af0 = *(const bf16x8*)(wp);
        bf16x8 af1 = *(const bf16x8*)(wp + 1024);
        bf16x8 af2 = *(const bf16x8*)(wp + 2048);
        bf16x8 af3 = *(const bf16x8*)(wp + 3072);
        int pbase = (ks * 4 + quad) * 221;
#pragma unroll
        for (int t = 0; t < 4; ++t) {
          if (t < ntcnt) {                 // wave-uniform
            bf16x8 bfr = *(const bf16x8*)&r1f[(pbase + pp[t]) * 8];
            acc[0][t] = __builtin_amdgcn_mfma_f32_16x16x32_bf16(af0, bfr, acc[0][t], 0, 0, 0);
            acc[1][t] = __builtin_amdgcn_mfma_f32_16x16x32_bf16(af1, bfr, acc[1][t], 0, 0, 0);
            acc[2][t] = __builtin_amdgcn_mfma_f32_16x16x32_bf16(af2, bfr, acc[2][t], 0, 0, 0);
            acc[3][t] = __builtin_amdgcn_mfma_f32_16x16x32_bf16(af3, bfr, acc[3][t], 0, 0, 0);
          }
        }
      }
    }

    // epilogue: BN2+SiLU, conv3 dot, reduce to scoreS
#pragma unroll
    for (int t = 0; t < 4; ++t) {
      if (t < ntcnt) {
        float ps = 0.f;
#pragma unroll
        for (int mt = 0; mt < 4; ++mt) {
#pragma unroll
          for (int r = 0; r < 4; ++r) {
            int o = wm * 64 + mt * 16 + quad * 4 + r;
            float y = acc[mt][t][r] * sc2[o] + sh2[o];
            ps += silu(y) * w3c[o];
          }
        }
        ps += __shfl_xor(ps, 16);
        ps += __shfl_xor(ps, 32);
        if (quad == 0 && pov[t]) atomicAdd(&scoreS[poA[t]], ps);
      }
    }
    __syncthreads();

    if (tid < 200) scoreS[tid] = silu(scoreS[tid] * s3 + sh3);
    __syncthreads();

    {
      int c = tid & 127, part = tid >> 7;
      float s = 0.f;
      int j0 = part * 50;
      for (int j = j0; j < j0 + 50; ++j)
        s += scoreS[j] * feat[(b * 400 + half * 200 + j) * 128 + c];
      atomicAdd(&attT[c], s);
    }
    __syncthreads();
    if (tid < 128)
      atomicAdd(&att[((size_t)(b * 400 + q)) * 128 + tid], attT[tid]);  // 2 addends: exact
  } else {
    // ================= const path (q < 200): r1 constant over pixels =================
    int cidx = blk - 800;
    int b = cidx / 200, q = cidx % 200;
    if (tid < 256) {
      int u = q * 256 + tid; int c = u / 400, i2 = u - c * 400;
      fA[tid] = featT[(b * 128 + c) * 400 + i2];           // coalesced
    }
    for (int k = tid; k < 1152; k += 512) vS[k] = 0.f;
    __syncthreads();
    {
      int o = tid & 127, part = tid >> 7;
      const float* wt = wr1T + part * 64 * 128 + o;        // coalesced across o
      const float* fv = fA + part * 64;
      float a = 0.f;
#pragma unroll 8
      for (int k = 0; k < 64; ++k) a += wt[k * 128] * fv[k];
      atomicAdd(&AvS[o], a);
    }
    __syncthreads();
    if (tid < 128) r1c[tid] = silu(AvS[tid] * sc1[tid] + sh1[tid]);
    __syncthreads();
    {
      int o = tid & 127, part = tid >> 7;
      const float* rc = r1c + part * 32;
      for (int tap = 0; tap < 9; ++tap) {
        const float* wt = Wt + tap * 16384 + part * 32 * 128 + o;
        float s = 0.f;
#pragma unroll 8
        for (int i2 = 0; i2 < 32; ++i2) s += wt[i2 * 128] * rc[i2];
        atomicAdd(&vS[tap * 128 + o], s);
      }
    }
    __syncthreads();
    for (int pat = wid; pat < 9; pat += 8) {
      int ry = pat / 3, rx = pat % 3;
      float ps = 0.f;
      for (int oo = lane; oo < 128; oo += 64) {
        float y = 0.f;
#pragma unroll
        for (int dy = -1; dy <= 1; ++dy) {
          if ((ry == 0 && dy < 0) || (ry == 2 && dy > 0)) continue;
#pragma unroll
          for (int dx = -1; dx <= 1; ++dx) {
            if ((rx == 0 && dx < 0) || (rx == 2 && dx > 0)) continue;
            y += vS[((dy + 1) * 3 + (dx + 1)) * 128 + oo];
          }
        }
        y = y * sc2[oo] + sh2[oo];
        ps += silu(y) * w3c[oo];
      }
#pragma unroll
      for (int sft = 32; sft >= 1; sft >>= 1) ps += __shfl_xor(ps, sft);
      if (lane == 0) spS[pat] = silu(ps * s3 + sh3);
    }
    __syncthreads();

    for (int p = tid; p < 400; p += 512) {
      int r = p / 20, cm = p - 20 * r;
      int ry = (r == 0) ? 0 : (r == 19) ? 2 : 1;
      int rx = (cm == 0) ? 0 : (cm == 19) ? 2 : 1;
      spP[p] = spS[ry * 3 + rx];
    }
    __syncthreads();
    {
      int c = tid & 127, part = tid >> 7;
      const float* fb = feat + ((size_t)(b * 400) + part * 100) * 128 + c;
      const float* sp = spP + part * 100;
      float s = 0.f;
      for (int j = 0; j < 100; ++j) s += sp[j] * fb[(size_t)j * 128];
      atomicAdd(&attT[c], s);
    }
    __syncthreads();
    if (tid < 128)
      att[((size_t)(b * 400 + q)) * 128 + tid] = attT[tid];
  }
}

// ---------------- out = SiLU(BN(conv1x1(att, w2))) + x   (1 px per 256-thr block, split-K pairs)
__global__ void out_kernel(const float* __restrict__ att, const float* __restrict__ x,
                           const float* __restrict__ w2,
                           const float* __restrict__ g2, const float* __restrict__ b2,
                           const float* __restrict__ m2, const float* __restrict__ v2,
                           float* __restrict__ out) {
  int pp = blockIdx.x;                 // 800
  int b = pp / 400, p = pp % 400;
  int tid = threadIdx.x;               // 256
  __shared__ float av[128];
  if (tid < 128) av[tid] = att[(size_t)(b * 400 + p) * 128 + tid];
  __syncthreads();
  int c = tid >> 1, part = tid & 1;
  const float4* w4 = (const float4*)(w2 + c * 128 + part * 64);
  const float4* v4 = (const float4*)(av + part * 64);
  float s0 = 0.f, s1 = 0.f, s2 = 0.f, s3 = 0.f;
#pragma unroll
  for (int i = 0; i < 16; ++i) {
    float4 wv = w4[i], xx = v4[i];
    s0 += wv.x * xx.x; s1 += wv.y * xx.y; s2 += wv.z * xx.z; s3 += wv.w * xx.w;
  }
  float s = (s0 + s1) + (s2 + s3);
  s += __shfl_xor(s, 1);
  if (part == 0) {
    float sc = g2[c] * rsqrtf(v2[c] + EPS);
    float y = s * sc + (b2[c] - m2[c] * sc);
    int xi = (b * 128 + c) * 400 + p;
    out[xi] = silu(y) + x[xi];
  }
}

extern "C" void kernel_launch(void* const* d_in, const int* in_sizes, int n_in,
                              void* d_out, int out_size, void* d_ws, size_t ws_size,
                              hipStream_t stream) {
  const float* x   = (const float*)d_in[0];
  const float* w1  = (const float*)d_in[1];
  const float* g1  = (const float*)d_in[2];
  const float* b1  = (const float*)d_in[3];
  const float* m1  = (const float*)d_in[4];
  const float* v1  = (const float*)d_in[5];
  const float* w2  = (const float*)d_in[6];
  const float* g2  = (const float*)d_in[7];
  const float* b2  = (const float*)d_in[8];
  const float* m2  = (const float*)d_in[9];
  const float* v2  = (const float*)d_in[10];
  const float* wr1 = (const float*)d_in[11];
  const float* gr1 = (const float*)d_in[12];
  const float* br1 = (const float*)d_in[13];
  const float* mr1 = (const float*)d_in[14];
  const float* vr1 = (const float*)d_in[15];
  const float* wr2 = (const float*)d_in[16];
  const float* gr2 = (const float*)d_in[17];
  const float* br2 = (const float*)d_in[18];
  const float* mr2 = (const float*)d_in[19];
  const float* vr2 = (const float*)d_in[20];
  const float* wr3 = (const float*)d_in[21];
  const float* gr3 = (const float*)d_in[22];
  const float* br3 = (const float*)d_in[23];
  const float* mr3 = (const float*)d_in[24];
  const float* vr3 = (const float*)d_in[25];
  float* out = (float*)d_out;

  char* ws = (char*)d_ws;
  float*          feat  = (float*)ws;                        // 409600 B
  float*          attb  = (float*)(ws + 409600);             // 409600 B
  unsigned short* Apack = (unsigned short*)(ws + 819200);    // 294912 B
  float*          Pfx   = (float*)(ws + 1114112);            // 131584 B
  float*          Wt    = (float*)(ws + 1245696);            // 589824 B
  float*          W2t   = (float*)(ws + 1835520);            //  65536 B
  float*          featT = (float*)(ws + 1901056);            // 409600 B
  float*          wr1T  = (float*)(ws + 2310656);            // 131072 B

  prep_kernel<<<744, 256, 0, stream>>>(x, w1, g1, b1, m1, v1, wr2, wr1, w2,
                                       feat, featT, attb, Apack, Pfx, Wt, W2t, wr1T);
  rel_kernel<<<1200, 512, 0, stream>>>(feat, featT, wr1T, Pfx, gr1, br1, mr1, vr1,
                                       Apack, Wt,
                                       gr2, br2, mr2, vr2, wr3, gr3, br3, mr3, vr3, attb);
  out_kernel<<<800, 256, 0, stream>>>(attb, x, w2, g2, b2, m2, v2, out);
}